// Round 16
// baseline (439.467 us; speedup 1.0000x reference)
//
#include <hip/hip_runtime.h>
#include <hip/hip_bf16.h>

#define N_NODES   10000
#define N_EDGES   320000
#define DIM       256
#define EDGE_DIM  64
#define FF_HIDDEN 512
#define GAMMA     0.5f
#define CHUNK     192          // LDS e-tile rows per chunk
#define VSTR      264          // LDS row stride bytes (fp8, 256+8 pad)

typedef __attribute__((ext_vector_type(8))) short bf16x8;
typedef __attribute__((ext_vector_type(4))) float f32x4;

static __device__ __forceinline__ unsigned short f2b(float f)
{
    union { __hip_bfloat16 b; unsigned short u; } c;
    c.b = __float2bfloat16(f);
    return c.u;
}
static __device__ __forceinline__ float b2fs(unsigned short u)
{
    union { unsigned u32; float f; } c;
    c.u32 = ((unsigned)u) << 16;
    return c.f;
}

// f32 -> fp8 e4m3fn (round-half-up, denormals flushed, clamp to 448).
static __device__ __forceinline__ unsigned f2fp8(float f)
{
    union { float f; unsigned u; } c; c.f = f;
    const unsigned s = (c.u >> 24) & 0x80u;
    int v = (int)(((c.u & 0x7FFFFFFFu) + 0x00080000u) >> 20) - 960;
    v = (v < 8) ? 0 : ((v > 126) ? 126 : v);
    return s | (unsigned)v;
}
// fp8 e4m3fn -> f32 (denormals -> 0)
static __device__ __forceinline__ float fp8tof(unsigned u)
{
    unsigned v = ((u & 0x7Fu) << 4) + 0x3C00u;
    v = (u & 0x78u) ? v : 0u;
    v |= (u & 0x80u) << 8;
    union { unsigned u; float f; } c; c.u = v << 16;
    return c.f;
}

static __device__ __forceinline__ bf16x8 load_a_frag(const float* __restrict__ p)
{
    const float4 f0 = *(const float4*)p;
    const float4 f1 = *(const float4*)(p + 4);
    bf16x8 r;
    r[0] = (short)f2b(f0.x); r[1] = (short)f2b(f0.y);
    r[2] = (short)f2b(f0.z); r[3] = (short)f2b(f0.w);
    r[4] = (short)f2b(f1.x); r[5] = (short)f2b(f1.y);
    r[6] = (short)f2b(f1.z); r[7] = (short)f2b(f1.w);
    return r;
}

// ---------------------------------------------------------------------------
__global__ __launch_bounds__(256) void detect_kernel(const unsigned* __restrict__ ei,
                                                     int* __restrict__ flag)
{
    __shared__ int bad;
    if (threadIdx.x == 0) bad = 0;
    __syncthreads();
    int b = 0;
    for (int i = threadIdx.x; i < 1024; i += 256)
        if (ei[2 * i + 1] != 0u) b = 1;
    if (b) atomicAdd(&bad, 1);
    __syncthreads();
    if (threadIdx.x == 0) *flag = (bad == 0) ? 1 : 0;
}

__global__ __launch_bounds__(256) void convert_kernel(const unsigned* __restrict__ ei,
                                                      const int* __restrict__ flag,
                                                      int* __restrict__ src, int* __restrict__ dst,
                                                      int* __restrict__ counts)
{
    const int i = blockIdx.x * 256 + threadIdx.x;
    if (i >= N_EDGES) return;
    const int f = *flag;
    int s, d;
    if (f) { s = (int)ei[2 * i]; d = (int)ei[2 * (N_EDGES + i)]; }
    else   { s = (int)ei[i];     d = (int)ei[N_EDGES + i]; }
    src[i] = s;
    dst[i] = d;
    atomicAdd(&counts[d], 1);
}

__global__ __launch_bounds__(256) void scan_kernel(const int* __restrict__ counts,
                                                   int* __restrict__ row_start)
{
    __shared__ int lds[256];
    const int t = threadIdx.x;
    int vals[40];
    int tot = 0;
    const int base = t * 40;
#pragma unroll
    for (int j = 0; j < 40; ++j) {
        const int idx = base + j;
        const int c = (idx < N_NODES) ? counts[idx] : 0;
        vals[j] = tot;
        tot += c;
    }
    lds[t] = tot;
    __syncthreads();
    for (int off = 1; off < 256; off <<= 1) {
        const int tmp = (t >= off) ? lds[t - off] : 0;
        __syncthreads();
        lds[t] += tmp;
        __syncthreads();
    }
    const int ebase = lds[t] - tot;
#pragma unroll
    for (int j = 0; j < 40; ++j) {
        const int idx = base + j;
        if (idx < N_NODES) row_start[idx] = ebase + vals[j];
    }
    if (t == 0) row_start[N_NODES] = N_EDGES;
}

// csr_eid[slot] = edge id, csr_src[slot] = source node.
__global__ __launch_bounds__(256) void fill_kernel(const int* __restrict__ src,
                                                   const int* __restrict__ dst,
                                                   const int* __restrict__ row_start,
                                                   int* __restrict__ fillc,
                                                   int* __restrict__ csr_eid,
                                                   int* __restrict__ csr_src)
{
    const int i = blockIdx.x * 256 + threadIdx.x;
    if (i >= N_EDGES) return;
    const int d = dst[i];
    const int pos = atomicAdd(&fillc[d], 1);
    const int slot = row_start[d] + pos;
    csr_eid[slot] = i;
    csr_src[slot] = src[i];
}

// ---------------------------------------------------------------------------
__global__ __launch_bounds__(256) void wconv_kernel(const float* __restrict__ W,
                                                    unsigned short* __restrict__ wT,
                                                    int K, int N)
{
    const int i = blockIdx.x * 256 + threadIdx.x;
    if (i >= K * N) return;
    const int k = i / N, n = i - k * N;
    wT[(size_t)n * K + k] = f2b(W[i]);
}

// edge_attr (f32, edge order) -> ea_bf (bf16, CSR slot order). 16 slots/block.
__global__ __launch_bounds__(256) void ea_conv(const float* __restrict__ ea,
                                               const int* __restrict__ csr_eid,
                                               unsigned short* __restrict__ out)
{
    const int slot = blockIdx.x * 16 + (threadIdx.x >> 4);
    const int l = threadIdx.x & 15;
    const int eid = csr_eid[slot];
    const float4 f = *(const float4*)(ea + (size_t)eid * EDGE_DIM + l * 4);
    ushort4 u;
    u.x = f2b(f.x); u.y = f2b(f.y); u.z = f2b(f.z); u.w = f2b(f.w);
    *(ushort4*)(out + (size_t)slot * EDGE_DIM + l * 4) = u;
}

// ---------------------------------------------------------------------------
// Wave-level register GEMM (no LDS), 4 waves/block, wave = 64x64 tile.
template <bool ABF16, int MODE>
__global__ __launch_bounds__(256) void wgemm(const void* __restrict__ Av,
                                             const unsigned short* __restrict__ wT,
                                             void* __restrict__ outv,
                                             int M, int K, int N,
                                             const unsigned short* __restrict__ epi_a,
                                             const float* __restrict__ epi_x)
{
    const int tid  = threadIdx.x;
    const int wave = tid >> 6;
    const int lane = tid & 63;
    const int l15  = lane & 15;
    const int l4   = lane >> 4;
    const int m0   = blockIdx.x * 64;
    const int n0   = blockIdx.y * 256 + wave * 64;

    f32x4 acc[4][4];
#pragma unroll
    for (int i = 0; i < 4; ++i)
#pragma unroll
        for (int j = 0; j < 4; ++j) acc[i][j] = f32x4{0.f, 0.f, 0.f, 0.f};

    int rowm[4];
#pragma unroll
    for (int i = 0; i < 4; ++i) rowm[i] = min(m0 + i * 16 + l15, M - 1);

    const int nk = K >> 6;
    for (int kt = 0; kt < nk; ++kt) {
        const int kb = kt * 64 + l4 * 8;
        bf16x8 bfr[2][4], afr[2][4];
#pragma unroll
        for (int ks = 0; ks < 2; ++ks)
#pragma unroll
            for (int j = 0; j < 4; ++j)
                bfr[ks][j] = *(const bf16x8*)(wT + (size_t)(n0 + j * 16 + l15) * K + kb + ks * 32);
#pragma unroll
        for (int ks = 0; ks < 2; ++ks)
#pragma unroll
            for (int i = 0; i < 4; ++i) {
                if (ABF16)
                    afr[ks][i] = *(const bf16x8*)((const unsigned short*)Av + (size_t)rowm[i] * K + kb + ks * 32);
                else
                    afr[ks][i] = load_a_frag((const float*)Av + (size_t)rowm[i] * K + kb + ks * 32);
            }
#pragma unroll
        for (int ks = 0; ks < 2; ++ks)
#pragma unroll
            for (int i = 0; i < 4; ++i)
#pragma unroll
                for (int j = 0; j < 4; ++j)
                    acc[i][j] = __builtin_amdgcn_mfma_f32_16x16x32_bf16(bfr[ks][j], afr[ks][i], acc[i][j], 0, 0, 0);
    }

#pragma unroll
    for (int i = 0; i < 4; ++i) {
        const int m = m0 + i * 16 + l15;
        if (m < M) {
#pragma unroll
            for (int j = 0; j < 4; ++j) {
                const size_t oi = (size_t)m * N + n0 + j * 16 + l4 * 4;
                if (MODE == 2) {
                    const ushort4 ea = *(const ushort4*)(epi_a + oi);
                    const float4  ex = *(const float4*)(epi_x + oi);
                    float4 v;
                    v.x = fmaxf(acc[i][j][0] + b2fs(ea.x), 0.f) + ex.x;
                    v.y = fmaxf(acc[i][j][1] + b2fs(ea.y), 0.f) + ex.y;
                    v.z = fmaxf(acc[i][j][2] + b2fs(ea.z), 0.f) + ex.z;
                    v.w = fmaxf(acc[i][j][3] + b2fs(ea.w), 0.f) + ex.w;
                    *(float4*)((float*)outv + oi) = v;
                } else {
                    float a0 = acc[i][j][0], a1 = acc[i][j][1];
                    float a2 = acc[i][j][2], a3 = acc[i][j][3];
                    if (MODE == 1) {
                        a0 = fmaxf(a0, 0.f); a1 = fmaxf(a1, 0.f);
                        a2 = fmaxf(a2, 0.f); a3 = fmaxf(a3, 0.f);
                    }
                    ushort4 u;
                    u.x = f2b(a0); u.y = f2b(a1); u.z = f2b(a2); u.w = f2b(a3);
                    *(ushort4*)((unsigned short*)outv + oi) = u;
                }
            }
        }
    }
}

// ---------------------------------------------------------------------------
// Fused hop v4: block = 4 COMPLETE nodes (grid 2500). Per chunk of <=192 CSR
// rows: phase 1 MFMA-recomputes e from ea_bf into LDS (fp8, conflict-free);
// phase 2 wave-per-node (r8-proven): full-row 512B h gathers, 8-deep MLP,
// register accumulation, direct h_out write. No egemm, no atomics, no fixup.
__global__ __launch_bounds__(256) void fused_hop(const unsigned short* __restrict__ h_prev1,
                                                 const unsigned short* __restrict__ h_prev2,
                                                 const unsigned short* __restrict__ ea,
                                                 const unsigned short* __restrict__ weT,
                                                 const int* __restrict__ row_start,
                                                 const int* __restrict__ csr_src,
                                                 unsigned short* __restrict__ h_out)
{
    __shared__ __align__(16) unsigned char val[CHUNK * VSTR];   // 50688 B

    const int tid  = threadIdx.x;
    const int wave = tid >> 6;
    const int lane = tid & 63;
    const int l15  = lane & 15;
    const int l4   = lane >> 4;
    const int wc0  = wave * 64;

    const int n0    = blockIdx.x * 4;
    const int rbase = row_start[n0];
    const int rend  = row_start[n0 + 4];
    const int n     = n0 + wave;                 // this wave's node
    const int rb    = row_start[n];
    const int re    = row_start[n + 1];

    // B fragments: wave's 64 output dims of W_e^T, hoisted once.
    bf16x8 bfr[2][4];
#pragma unroll
    for (int ks = 0; ks < 2; ++ks)
#pragma unroll
        for (int j = 0; j < 4; ++j)
            bfr[ks][j] = *(const bf16x8*)(weT + (size_t)(wc0 + j * 16 + l15) * 64 + ks * 32 + l4 * 8);

    float hx = 0.f, hy = 0.f, hz = 0.f, hw = 0.f;

    for (int c0 = rbase; c0 < rend; c0 += CHUNK) {
        const int cn = min(CHUNK, rend - c0);
        __syncthreads();   // protect LDS from previous chunk's readers

        // ---- Phase 1: e rows [c0, c0+cn) -> LDS fp8
        for (int rt = 0; rt * 16 < cn; ++rt) {
            const int arow = min(c0 + rt * 16 + l15, N_EDGES - 1);
            bf16x8 afr[2];
#pragma unroll
            for (int ks = 0; ks < 2; ++ks)
                afr[ks] = *(const bf16x8*)(ea + (size_t)arow * 64 + ks * 32 + l4 * 8);
            f32x4 acc[4];
#pragma unroll
            for (int j = 0; j < 4; ++j) acc[j] = f32x4{0.f, 0.f, 0.f, 0.f};
#pragma unroll
            for (int ks = 0; ks < 2; ++ks)
#pragma unroll
                for (int j = 0; j < 4; ++j)
                    acc[j] = __builtin_amdgcn_mfma_f32_16x16x32_bf16(bfr[ks][j], afr[ks], acc[j], 0, 0, 0);
#pragma unroll
            for (int j = 0; j < 4; ++j) {
                const unsigned p = f2fp8(acc[j][0])
                                 | (f2fp8(acc[j][1]) << 8)
                                 | (f2fp8(acc[j][2]) << 16)
                                 | (f2fp8(acc[j][3]) << 24);
                *(unsigned*)(&val[(rt * 16 + l15) * VSTR + wc0 + j * 16 + l4 * 4]) = p;
            }
        }
        __syncthreads();

        // ---- Phase 2: wave-per-node over its in-chunk slots
        const int sb = max(rb, c0);
        const int se = min(re, c0 + cn);
        int s = sb;
        for (; s + 8 <= se; s += 8) {
            int sr[8];
            unsigned ev[8];
            ushort4 hv[8];
#pragma unroll
            for (int u = 0; u < 8; ++u) sr[u] = csr_src[s + u];
#pragma unroll
            for (int u = 0; u < 8; ++u)
                ev[u] = *(const unsigned*)(&val[(s + u - c0) * VSTR + lane * 4]);
#pragma unroll
            for (int u = 0; u < 8; ++u)
                hv[u] = *(const ushort4*)(h_prev1 + (size_t)sr[u] * DIM + lane * 4);
#pragma unroll
            for (int u = 0; u < 8; ++u) {
                hx += fmaxf(b2fs(hv[u].x) + fp8tof(ev[u] & 255u), 0.f);
                hy += fmaxf(b2fs(hv[u].y) + fp8tof((ev[u] >> 8) & 255u), 0.f);
                hz += fmaxf(b2fs(hv[u].z) + fp8tof((ev[u] >> 16) & 255u), 0.f);
                hw += fmaxf(b2fs(hv[u].w) + fp8tof(ev[u] >> 24), 0.f);
            }
        }
        for (; s < se; ++s) {
            const int sr = csr_src[s];
            const unsigned ev = *(const unsigned*)(&val[(s - c0) * VSTR + lane * 4]);
            const ushort4 hv = *(const ushort4*)(h_prev1 + (size_t)sr * DIM + lane * 4);
            hx += fmaxf(b2fs(hv.x) + fp8tof(ev & 255u), 0.f);
            hy += fmaxf(b2fs(hv.y) + fp8tof((ev >> 8) & 255u), 0.f);
            hz += fmaxf(b2fs(hv.z) + fp8tof((ev >> 16) & 255u), 0.f);
            hw += fmaxf(b2fs(hv.w) + fp8tof(ev >> 24), 0.f);
        }
    }

    if (h_prev2) {
        const float gd = GAMMA * (float)(re - rb);
        const ushort4 p2 = *(const ushort4*)(h_prev2 + (size_t)n * DIM + lane * 4);
        hx -= gd * b2fs(p2.x); hy -= gd * b2fs(p2.y);
        hz -= gd * b2fs(p2.z); hw -= gd * b2fs(p2.w);
    }
    ushort4 o;
    o.x = f2b(hx); o.y = f2b(hy); o.z = f2b(hz); o.w = f2b(hw);
    *(ushort4*)(h_out + (size_t)n * DIM + lane * 4) = o;
}

// ---------------------------------------------------------------------------
__global__ __launch_bounds__(256) void attn_kernel(const unsigned short* __restrict__ h0,
                                                   const unsigned short* __restrict__ h1,
                                                   const unsigned short* __restrict__ h2,
                                                   const unsigned short* __restrict__ h3,
                                                   const float* __restrict__ att_a,
                                                   unsigned short* __restrict__ out)
{
    const int n = blockIdx.x;
    const int t = threadIdx.x;
    const size_t i = (size_t)n * DIM + t;
    const float q = b2fs(h0[i]);
    float hk[4];
    hk[0] = q; hk[1] = b2fs(h1[i]); hk[2] = b2fs(h2[i]); hk[3] = b2fs(h3[i]);
    const float a = att_a[t];
    float sc[4];
#pragma unroll
    for (int k = 0; k < 4; ++k) {
        float v = tanhf(hk[k] + q) * a;
#pragma unroll
        for (int off = 32; off > 0; off >>= 1)
            v += __shfl_xor(v, off, 64);
        sc[k] = v;
    }
    const float mx = fmaxf(fmaxf(sc[0], sc[1]), fmaxf(sc[2], sc[3]));
    float ex[4], se = 0.f;
#pragma unroll
    for (int k = 0; k < 4; ++k) { ex[k] = __expf(sc[k] - mx); se += ex[k]; }
    const float inv = 1.f / se;
    float o = 0.f;
#pragma unroll
    for (int k = 0; k < 4; ++k) o += ex[k] * inv * hk[k];
    out[i] = f2b(o);
}

// ---------------------------------------------------------------------------
extern "C" void kernel_launch(void* const* d_in, const int* in_sizes, int n_in,
                              void* d_out, int out_size, void* d_ws, size_t ws_size,
                              hipStream_t stream)
{
    const float*    x         = (const float*)d_in[0];
    const unsigned* ei        = (const unsigned*)d_in[1];
    const float*    edge_attr = (const float*)d_in[2];
    const float*    W_x       = (const float*)d_in[3];
    const float*    W_e       = (const float*)d_in[4];
    const float*    att_a     = (const float*)d_in[5];
    const float*    W_ff1     = (const float*)d_in[6];
    const float*    W_ff2     = (const float*)d_in[7];

    char* ws = (char*)d_ws;
    size_t off = 0;
    auto alloc = [&](size_t bytes) -> void* {
        void* p = ws + off;
        off = (off + bytes + 255) & ~(size_t)255;
        return p;
    };
    int*   flag      = (int*)alloc(4);
    int*   src32     = (int*)alloc((size_t)N_EDGES * 4);
    int*   dst32     = (int*)alloc((size_t)N_EDGES * 4);
    int*   counts    = (int*)alloc((size_t)2 * N_NODES * 4);
    int*   fillc     = counts + N_NODES;
    int*   row_start = (int*)alloc((size_t)(N_NODES + 1) * 4);
    int*   csr_eid   = (int*)alloc((size_t)N_EDGES * 4);
    int*   csr_src   = (int*)alloc((size_t)N_EDGES * 4);
    unsigned short* ea_bf = (unsigned short*)alloc((size_t)N_EDGES * EDGE_DIM * 2);
    unsigned short* h0b   = (unsigned short*)alloc((size_t)N_NODES * DIM * 2);
    unsigned short* h1b   = (unsigned short*)alloc((size_t)N_NODES * DIM * 2);
    unsigned short* h2b   = (unsigned short*)alloc((size_t)N_NODES * DIM * 2);
    unsigned short* h3b   = (unsigned short*)alloc((size_t)N_NODES * DIM * 2);
    unsigned short* attnb = (unsigned short*)alloc((size_t)N_NODES * DIM * 2);
    unsigned short* hidb  = (unsigned short*)alloc((size_t)N_NODES * FF_HIDDEN * 2);
    unsigned short* wxT   = (unsigned short*)alloc((size_t)DIM * DIM * 2);
    unsigned short* weT   = (unsigned short*)alloc((size_t)DIM * EDGE_DIM * 2);
    unsigned short* wff1T = (unsigned short*)alloc((size_t)FF_HIDDEN * DIM * 2);
    unsigned short* wff2T = (unsigned short*)alloc((size_t)DIM * FF_HIDDEN * 2);
    if (off > ws_size) return;

    const int egrid = (N_EDGES + 255) / 256;

    hipMemsetAsync(counts, 0, (size_t)2 * N_NODES * 4, stream);
    detect_kernel<<<1, 256, 0, stream>>>(ei, flag);
    convert_kernel<<<egrid, 256, 0, stream>>>(ei, flag, src32, dst32, counts);
    scan_kernel<<<1, 256, 0, stream>>>(counts, row_start);
    fill_kernel<<<egrid, 256, 0, stream>>>(src32, dst32, row_start, fillc, csr_eid, csr_src);

    wconv_kernel<<<(DIM * DIM + 255) / 256, 256, 0, stream>>>(W_x, wxT, DIM, DIM);
    wconv_kernel<<<(EDGE_DIM * DIM + 255) / 256, 256, 0, stream>>>(W_e, weT, EDGE_DIM, DIM);
    wconv_kernel<<<(DIM * FF_HIDDEN + 255) / 256, 256, 0, stream>>>(W_ff1, wff1T, DIM, FF_HIDDEN);
    wconv_kernel<<<(FF_HIDDEN * DIM + 255) / 256, 256, 0, stream>>>(W_ff2, wff2T, FF_HIDDEN, DIM);

    // CSR-ordered bf16 edge features (41 MB; each hop recomputes e from this)
    ea_conv<<<N_EDGES / 16, 256, 0, stream>>>(edge_attr, csr_eid, ea_bf);

    // h0 = x @ W_x -> bf16
    wgemm<false, 0><<<dim3(157, 1), 256, 0, stream>>>(x, wxT, h0b,
        N_NODES, DIM, DIM, nullptr, nullptr);

    fused_hop<<<N_NODES / 4, 256, 0, stream>>>(h0b, nullptr, ea_bf, weT, row_start, csr_src, h1b);
    fused_hop<<<N_NODES / 4, 256, 0, stream>>>(h1b, h0b,     ea_bf, weT, row_start, csr_src, h2b);
    fused_hop<<<N_NODES / 4, 256, 0, stream>>>(h2b, h1b,     ea_bf, weT, row_start, csr_src, h3b);

    attn_kernel<<<N_NODES, 256, 0, stream>>>(h0b, h1b, h2b, h3b, att_a, attnb);

    // hidden = relu(attn @ W_ff1) -> bf16
    wgemm<true, 1><<<dim3(157, 2), 256, 0, stream>>>(attnb, wff1T, hidb,
        N_NODES, DIM, FF_HIDDEN, nullptr, nullptr);
    // d_out = x + relu(attn + hidden @ W_ff2)
    wgemm<true, 2><<<dim3(157, 1), 256, 0, stream>>>(hidb, wff2T, d_out,
        N_NODES, FF_HIDDEN, DIM, attnb, x);
}

// Round 17
// 345.427 us; speedup vs baseline: 1.2722x; 1.2722x over previous
//
#include <hip/hip_runtime.h>
#include <hip/hip_bf16.h>

#define N_NODES   10000
#define N_EDGES   320000
#define DIM       256
#define EDGE_DIM  64
#define FF_HIDDEN 512
#define GAMMA     0.5f

typedef __attribute__((ext_vector_type(8))) short bf16x8;
typedef __attribute__((ext_vector_type(4))) float f32x4;

static __device__ __forceinline__ unsigned short f2b(float f)
{
    union { __hip_bfloat16 b; unsigned short u; } c;
    c.b = __float2bfloat16(f);
    return c.u;
}
static __device__ __forceinline__ float b2fs(unsigned short u)
{
    union { unsigned u32; float f; } c;
    c.u32 = ((unsigned)u) << 16;
    return c.f;
}

// f32 -> fp8 e4m3fn (round-half-up, denormals flushed, clamp to 448).
static __device__ __forceinline__ unsigned f2fp8(float f)
{
    union { float f; unsigned u; } c; c.f = f;
    const unsigned s = (c.u >> 24) & 0x80u;
    int v = (int)(((c.u & 0x7FFFFFFFu) + 0x00080000u) >> 20) - 960;
    v = (v < 8) ? 0 : ((v > 126) ? 126 : v);
    return s | (unsigned)v;
}
// fp8 e4m3fn -> f32 (denormals -> 0)
static __device__ __forceinline__ float fp8tof(unsigned u)
{
    unsigned v = ((u & 0x7Fu) << 4) + 0x3C00u;
    v = (u & 0x78u) ? v : 0u;
    v |= (u & 0x80u) << 8;
    union { unsigned u; float f; } c; c.u = v << 16;
    return c.f;
}

static __device__ __forceinline__ bf16x8 load_a_frag(const float* __restrict__ p)
{
    const float4 f0 = *(const float4*)p;
    const float4 f1 = *(const float4*)(p + 4);
    bf16x8 r;
    r[0] = (short)f2b(f0.x); r[1] = (short)f2b(f0.y);
    r[2] = (short)f2b(f0.z); r[3] = (short)f2b(f0.w);
    r[4] = (short)f2b(f1.x); r[5] = (short)f2b(f1.y);
    r[6] = (short)f2b(f1.z); r[7] = (short)f2b(f1.w);
    return r;
}

// ---------------------------------------------------------------------------
__global__ __launch_bounds__(256) void detect_kernel(const unsigned* __restrict__ ei,
                                                     int* __restrict__ flag)
{
    __shared__ int bad;
    if (threadIdx.x == 0) bad = 0;
    __syncthreads();
    int b = 0;
    for (int i = threadIdx.x; i < 1024; i += 256)
        if (ei[2 * i + 1] != 0u) b = 1;
    if (b) atomicAdd(&bad, 1);
    __syncthreads();
    if (threadIdx.x == 0) *flag = (bad == 0) ? 1 : 0;
}

static __device__ __forceinline__ void wconv_elem(const float* __restrict__ W,
                                                  unsigned short* __restrict__ wT,
                                                  int N, int K, int i)
{
    const int k = i / N, n = i - k * N;
    wT[(size_t)n * K + k] = f2b(W[i]);
}

// Combined prep: blocks [0,1250) convert edge_index + count degrees;
// blocks [1250,2594) convert the four weight matrices to bf16^T.
#define CONV_BLOCKS 1250
__global__ __launch_bounds__(256) void prep_kernel(const unsigned* __restrict__ ei,
                                                   const int* __restrict__ flag,
                                                   int* __restrict__ src, int* __restrict__ dst,
                                                   int* __restrict__ counts,
                                                   const float* __restrict__ W_x,
                                                   const float* __restrict__ W_e,
                                                   const float* __restrict__ W_ff1,
                                                   const float* __restrict__ W_ff2,
                                                   unsigned short* __restrict__ wxT,
                                                   unsigned short* __restrict__ weT,
                                                   unsigned short* __restrict__ wff1T,
                                                   unsigned short* __restrict__ wff2T)
{
    const int bx = blockIdx.x;
    if (bx < CONV_BLOCKS) {
        const int i = bx * 256 + threadIdx.x;
        if (i >= N_EDGES) return;
        const int f = *flag;
        int s, d;
        if (f) { s = (int)ei[2 * i]; d = (int)ei[2 * (N_EDGES + i)]; }
        else   { s = (int)ei[i];     d = (int)ei[N_EDGES + i]; }
        src[i] = s;
        dst[i] = d;
        atomicAdd(&counts[d], 1);
    } else {
        const int i = (bx - CONV_BLOCKS) * 256 + threadIdx.x;
        // segments: W_x 65536 | W_e 16384 | W_ff1 131072 | W_ff2 131072
        if (i < 65536)        wconv_elem(W_x,   wxT,   DIM,       DIM,       i);
        else if (i < 81920)   wconv_elem(W_e,   weT,   DIM,       EDGE_DIM,  i - 65536);
        else if (i < 212992)  wconv_elem(W_ff1, wff1T, FF_HIDDEN, DIM,       i - 81920);
        else if (i < 344064)  wconv_elem(W_ff2, wff2T, DIM,       FF_HIDDEN, i - 212992);
    }
}

__global__ __launch_bounds__(256) void scan_kernel(const int* __restrict__ counts,
                                                   int* __restrict__ row_start)
{
    __shared__ int lds[256];
    const int t = threadIdx.x;
    int vals[40];
    int tot = 0;
    const int base = t * 40;
#pragma unroll
    for (int j = 0; j < 40; ++j) {
        const int idx = base + j;
        const int c = (idx < N_NODES) ? counts[idx] : 0;
        vals[j] = tot;
        tot += c;
    }
    lds[t] = tot;
    __syncthreads();
    for (int off = 1; off < 256; off <<= 1) {
        const int tmp = (t >= off) ? lds[t - off] : 0;
        __syncthreads();
        lds[t] += tmp;
        __syncthreads();
    }
    const int ebase = lds[t] - tot;
#pragma unroll
    for (int j = 0; j < 40; ++j) {
        const int idx = base + j;
        if (idx < N_NODES) row_start[idx] = ebase + vals[j];
    }
    if (t == 0) row_start[N_NODES] = N_EDGES;
}

// perm[edge] = CSR slot (for egemm scatter stores); csr_src[slot] = src node.
__global__ __launch_bounds__(256) void fill_kernel(const int* __restrict__ src,
                                                   const int* __restrict__ dst,
                                                   const int* __restrict__ row_start,
                                                   int* __restrict__ fillc,
                                                   int* __restrict__ perm,
                                                   int* __restrict__ csr_src)
{
    const int i = blockIdx.x * 256 + threadIdx.x;
    if (i >= N_EDGES) return;
    const int d = dst[i];
    const int pos = atomicAdd(&fillc[d], 1);
    const int slot = row_start[d] + pos;
    perm[i] = slot;
    csr_src[slot] = src[i];
}

// ---------------------------------------------------------------------------
// wgemm body (device function): out[M][N] = A @ W (wT bf16 [N][K]).
// 4 waves/block, wave = 64x64 tile. Swapped-operand MFMA.
template <bool ABF16, int MODE>
static __device__ __forceinline__ void wgemm_body(const void* __restrict__ Av,
                                                  const unsigned short* __restrict__ wT,
                                                  void* __restrict__ outv,
                                                  int M, int K, int N,
                                                  const unsigned short* __restrict__ epi_a,
                                                  const float* __restrict__ epi_x,
                                                  int bx, int by)
{
    const int tid  = threadIdx.x;
    const int wave = tid >> 6;
    const int lane = tid & 63;
    const int l15  = lane & 15;
    const int l4   = lane >> 4;
    const int m0   = bx * 64;
    const int n0   = by * 256 + wave * 64;

    f32x4 acc[4][4];
#pragma unroll
    for (int i = 0; i < 4; ++i)
#pragma unroll
        for (int j = 0; j < 4; ++j) acc[i][j] = f32x4{0.f, 0.f, 0.f, 0.f};

    int rowm[4];
#pragma unroll
    for (int i = 0; i < 4; ++i) rowm[i] = min(m0 + i * 16 + l15, M - 1);

    const int nk = K >> 6;
    for (int kt = 0; kt < nk; ++kt) {
        const int kb = kt * 64 + l4 * 8;
        bf16x8 bfr[2][4], afr[2][4];
#pragma unroll
        for (int ks = 0; ks < 2; ++ks)
#pragma unroll
            for (int j = 0; j < 4; ++j)
                bfr[ks][j] = *(const bf16x8*)(wT + (size_t)(n0 + j * 16 + l15) * K + kb + ks * 32);
#pragma unroll
        for (int ks = 0; ks < 2; ++ks)
#pragma unroll
            for (int i = 0; i < 4; ++i) {
                if (ABF16)
                    afr[ks][i] = *(const bf16x8*)((const unsigned short*)Av + (size_t)rowm[i] * K + kb + ks * 32);
                else
                    afr[ks][i] = load_a_frag((const float*)Av + (size_t)rowm[i] * K + kb + ks * 32);
            }
#pragma unroll
        for (int ks = 0; ks < 2; ++ks)
#pragma unroll
            for (int i = 0; i < 4; ++i)
#pragma unroll
                for (int j = 0; j < 4; ++j)
                    acc[i][j] = __builtin_amdgcn_mfma_f32_16x16x32_bf16(bfr[ks][j], afr[ks][i], acc[i][j], 0, 0, 0);
    }

#pragma unroll
    for (int i = 0; i < 4; ++i) {
        const int m = m0 + i * 16 + l15;
        if (m < M) {
#pragma unroll
            for (int j = 0; j < 4; ++j) {
                const size_t oi = (size_t)m * N + n0 + j * 16 + l4 * 4;
                if (MODE == 2) {
                    const ushort4 ea = *(const ushort4*)(epi_a + oi);
                    const float4  ex = *(const float4*)(epi_x + oi);
                    float4 v;
                    v.x = fmaxf(acc[i][j][0] + b2fs(ea.x), 0.f) + ex.x;
                    v.y = fmaxf(acc[i][j][1] + b2fs(ea.y), 0.f) + ex.y;
                    v.z = fmaxf(acc[i][j][2] + b2fs(ea.z), 0.f) + ex.z;
                    v.w = fmaxf(acc[i][j][3] + b2fs(ea.w), 0.f) + ex.w;
                    *(float4*)((float*)outv + oi) = v;
                } else {
                    float a0 = acc[i][j][0], a1 = acc[i][j][1];
                    float a2 = acc[i][j][2], a3 = acc[i][j][3];
                    if (MODE == 1) {
                        a0 = fmaxf(a0, 0.f); a1 = fmaxf(a1, 0.f);
                        a2 = fmaxf(a2, 0.f); a3 = fmaxf(a3, 0.f);
                    }
                    ushort4 u;
                    u.x = f2b(a0); u.y = f2b(a1); u.z = f2b(a2); u.w = f2b(a3);
                    *(ushort4*)((unsigned short*)outv + oi) = u;
                }
            }
        }
    }
}

template <bool ABF16, int MODE>
__global__ __launch_bounds__(256) void wgemm(const void* __restrict__ Av,
                                             const unsigned short* __restrict__ wT,
                                             void* __restrict__ outv,
                                             int M, int K, int N,
                                             const unsigned short* __restrict__ epi_a,
                                             const float* __restrict__ epi_x)
{
    wgemm_body<ABF16, MODE>(Av, wT, outv, M, K, N, epi_a, epi_x,
                            blockIdx.x, blockIdx.y);
}

// ---------------------------------------------------------------------------
// Combined dispatch: blocks [0,5000) = e-GEMM->fp8 (r13 scatter-store flavor,
// sequential edge reads, 256B-row scatter to CSR slot); blocks [5000,5157) =
// h0 = x @ W_x (runs in egemm's latency shadow).
#define EGEMM_BLOCKS (N_EDGES / 64)
__global__ __launch_bounds__(256) void egemm_h0(const float* __restrict__ A,
                                                const unsigned short* __restrict__ weT,
                                                unsigned char* __restrict__ e_out,
                                                const int* __restrict__ perm,
                                                const float* __restrict__ x,
                                                const unsigned short* __restrict__ wxT,
                                                unsigned short* __restrict__ h0b)
{
    if (blockIdx.x >= EGEMM_BLOCKS) {
        wgemm_body<false, 0>(x, wxT, h0b, N_NODES, DIM, DIM, nullptr, nullptr,
                             blockIdx.x - EGEMM_BLOCKS, 0);
        return;
    }
    __shared__ unsigned char et[64 * 272];   // 17408 B
    const int tid  = threadIdx.x;
    const int wave = tid >> 6;
    const int lane = tid & 63;
    const int l15  = lane & 15;
    const int l4   = lane >> 4;
    const int wc0  = wave * 64;
    const int m0   = blockIdx.x * 64;   // edge base (sequential)

    bf16x8 bfr[2][4];
#pragma unroll
    for (int ks = 0; ks < 2; ++ks)
#pragma unroll
        for (int j = 0; j < 4; ++j)
            bfr[ks][j] = *(const bf16x8*)(weT + (size_t)(wc0 + j * 16 + l15) * 64 + ks * 32 + l4 * 8);

    bf16x8 afr[2][4];
#pragma unroll
    for (int ks = 0; ks < 2; ++ks)
#pragma unroll
        for (int i = 0; i < 4; ++i)
            afr[ks][i] = load_a_frag(A + (size_t)(m0 + i * 16 + l15) * 64 + ks * 32 + l4 * 8);

    f32x4 acc[4][4];
#pragma unroll
    for (int i = 0; i < 4; ++i)
#pragma unroll
        for (int j = 0; j < 4; ++j) acc[i][j] = f32x4{0.f, 0.f, 0.f, 0.f};
#pragma unroll
    for (int ks = 0; ks < 2; ++ks)
#pragma unroll
        for (int i = 0; i < 4; ++i)
#pragma unroll
            for (int j = 0; j < 4; ++j)
                acc[i][j] = __builtin_amdgcn_mfma_f32_16x16x32_bf16(bfr[ks][j], afr[ks][i], acc[i][j], 0, 0, 0);

#pragma unroll
    for (int i = 0; i < 4; ++i)
#pragma unroll
        for (int j = 0; j < 4; ++j) {
            const unsigned p = f2fp8(acc[i][j][0])
                             | (f2fp8(acc[i][j][1]) << 8)
                             | (f2fp8(acc[i][j][2]) << 16)
                             | (f2fp8(acc[i][j][3]) << 24);
            *(unsigned*)(&et[(i * 16 + l15) * 272 + wc0 + j * 16 + l4 * 4]) = p;
        }
    __syncthreads();

    const int row  = tid >> 2;
    const int orow = perm[m0 + row];
    const unsigned char* sp = et + row * 272 + (tid & 3) * 64;
    unsigned char* dp = e_out + (size_t)orow * 256 + (tid & 3) * 64;
#pragma unroll
    for (int v = 0; v < 4; ++v)
        *(uint4*)(dp + v * 16) = *(const uint4*)(sp + v * 16);
}

// ---------------------------------------------------------------------------
// Hop (r13-best): wave-per-node, 4 dims/lane, 8-edge MLP unroll.
// e fp8 in CSR order (sequential 256B rows); h bf16 full-row gathers.
__global__ __launch_bounds__(256) void hop_kernel(const unsigned short* __restrict__ h_prev1,
                                                  const unsigned short* __restrict__ h_prev2,
                                                  const unsigned char* __restrict__ e,
                                                  const int* __restrict__ row_start,
                                                  const int* __restrict__ csr_src,
                                                  unsigned short* __restrict__ h_out)
{
    const int wave = threadIdx.x >> 6;
    const int lane = threadIdx.x & 63;
    const int n = blockIdx.x * 4 + wave;
    const int d4 = lane * 4;
    const int rb = row_start[n];
    const int re = row_start[n + 1];

    float4 acc = {0.f, 0.f, 0.f, 0.f};
    int s = rb;
    for (; s + 8 <= re; s += 8) {
        int idx[8];
        unsigned ev[8];
        ushort4 hv[8];
#pragma unroll
        for (int u = 0; u < 8; ++u) idx[u] = csr_src[s + u];
#pragma unroll
        for (int u = 0; u < 8; ++u) ev[u] = *(const unsigned*)(e + (size_t)(s + u) * 256 + d4);
#pragma unroll
        for (int u = 0; u < 8; ++u) hv[u] = *(const ushort4*)(h_prev1 + (size_t)idx[u] * DIM + d4);
#pragma unroll
        for (int u = 0; u < 8; ++u) {
            acc.x += fmaxf(b2fs(hv[u].x) + fp8tof(ev[u] & 255u), 0.f);
            acc.y += fmaxf(b2fs(hv[u].y) + fp8tof((ev[u] >> 8) & 255u), 0.f);
            acc.z += fmaxf(b2fs(hv[u].z) + fp8tof((ev[u] >> 16) & 255u), 0.f);
            acc.w += fmaxf(b2fs(hv[u].w) + fp8tof(ev[u] >> 24), 0.f);
        }
    }
    for (; s < re; ++s) {
        const int sr = csr_src[s];
        const unsigned ev = *(const unsigned*)(e + (size_t)s * 256 + d4);
        const ushort4 hv = *(const ushort4*)(h_prev1 + (size_t)sr * DIM + d4);
        acc.x += fmaxf(b2fs(hv.x) + fp8tof(ev & 255u), 0.f);
        acc.y += fmaxf(b2fs(hv.y) + fp8tof((ev >> 8) & 255u), 0.f);
        acc.z += fmaxf(b2fs(hv.z) + fp8tof((ev >> 16) & 255u), 0.f);
        acc.w += fmaxf(b2fs(hv.w) + fp8tof(ev >> 24), 0.f);
    }
    if (h_prev2) {
        const float gd = GAMMA * (float)(re - rb);
        const ushort4 p2 = *(const ushort4*)(h_prev2 + (size_t)n * DIM + d4);
        acc.x -= gd * b2fs(p2.x); acc.y -= gd * b2fs(p2.y);
        acc.z -= gd * b2fs(p2.z); acc.w -= gd * b2fs(p2.w);
    }
    ushort4 o;
    o.x = f2b(acc.x); o.y = f2b(acc.y); o.z = f2b(acc.z); o.w = f2b(acc.w);
    *(ushort4*)(h_out + (size_t)n * DIM + d4) = o;
}

// ---------------------------------------------------------------------------
__global__ __launch_bounds__(256) void attn_kernel(const unsigned short* __restrict__ h0,
                                                   const unsigned short* __restrict__ h1,
                                                   const unsigned short* __restrict__ h2,
                                                   const unsigned short* __restrict__ h3,
                                                   const float* __restrict__ att_a,
                                                   unsigned short* __restrict__ out)
{
    const int n = blockIdx.x;
    const int t = threadIdx.x;
    const size_t i = (size_t)n * DIM + t;
    const float q = b2fs(h0[i]);
    float hk[4];
    hk[0] = q; hk[1] = b2fs(h1[i]); hk[2] = b2fs(h2[i]); hk[3] = b2fs(h3[i]);
    const float a = att_a[t];
    float sc[4];
#pragma unroll
    for (int k = 0; k < 4; ++k) {
        float v = tanhf(hk[k] + q) * a;
#pragma unroll
        for (int off = 32; off > 0; off >>= 1)
            v += __shfl_xor(v, off, 64);
        sc[k] = v;
    }
    const float mx = fmaxf(fmaxf(sc[0], sc[1]), fmaxf(sc[2], sc[3]));
    float ex[4], se = 0.f;
#pragma unroll
    for (int k = 0; k < 4; ++k) { ex[k] = __expf(sc[k] - mx); se += ex[k]; }
    const float inv = 1.f / se;
    float o = 0.f;
#pragma unroll
    for (int k = 0; k < 4; ++k) o += ex[k] * inv * hk[k];
    out[i] = f2b(o);
}

// ---------------------------------------------------------------------------
extern "C" void kernel_launch(void* const* d_in, const int* in_sizes, int n_in,
                              void* d_out, int out_size, void* d_ws, size_t ws_size,
                              hipStream_t stream)
{
    const float*    x         = (const float*)d_in[0];
    const unsigned* ei        = (const unsigned*)d_in[1];
    const float*    edge_attr = (const float*)d_in[2];
    const float*    W_x       = (const float*)d_in[3];
    const float*    W_e       = (const float*)d_in[4];
    const float*    att_a     = (const float*)d_in[5];
    const float*    W_ff1     = (const float*)d_in[6];
    const float*    W_ff2     = (const float*)d_in[7];

    char* ws = (char*)d_ws;
    size_t off = 0;
    auto alloc = [&](size_t bytes) -> void* {
        void* p = ws + off;
        off = (off + bytes + 255) & ~(size_t)255;
        return p;
    };
    int*   flag      = (int*)alloc(4);
    int*   src32     = (int*)alloc((size_t)N_EDGES * 4);
    int*   dst32     = (int*)alloc((size_t)N_EDGES * 4);
    int*   counts    = (int*)alloc((size_t)2 * N_NODES * 4);
    int*   fillc     = counts + N_NODES;
    int*   row_start = (int*)alloc((size_t)(N_NODES + 1) * 4);
    int*   perm      = (int*)alloc((size_t)N_EDGES * 4);
    int*   csr_src   = (int*)alloc((size_t)N_EDGES * 4);
    unsigned char*  e_fp8 = (unsigned char*)alloc((size_t)N_EDGES * DIM);
    unsigned short* h0b   = (unsigned short*)alloc((size_t)N_NODES * DIM * 2);
    unsigned short* h1b   = (unsigned short*)alloc((size_t)N_NODES * DIM * 2);
    unsigned short* h2b   = (unsigned short*)alloc((size_t)N_NODES * DIM * 2);
    unsigned short* h3b   = (unsigned short*)alloc((size_t)N_NODES * DIM * 2);
    unsigned short* attnb = (unsigned short*)alloc((size_t)N_NODES * DIM * 2);
    unsigned short* hidb  = (unsigned short*)alloc((size_t)N_NODES * FF_HIDDEN * 2);
    unsigned short* wxT   = (unsigned short*)alloc((size_t)DIM * DIM * 2);
    unsigned short* weT   = (unsigned short*)alloc((size_t)DIM * EDGE_DIM * 2);
    unsigned short* wff1T = (unsigned short*)alloc((size_t)FF_HIDDEN * DIM * 2);
    unsigned short* wff2T = (unsigned short*)alloc((size_t)DIM * FF_HIDDEN * 2);
    if (off > ws_size) return;

    hipMemsetAsync(counts, 0, (size_t)2 * N_NODES * 4, stream);
    detect_kernel<<<1, 256, 0, stream>>>(ei, flag);
    // convert (1250 blocks) + all four weight transposes (1344 blocks)
    prep_kernel<<<CONV_BLOCKS + 1344, 256, 0, stream>>>(ei, flag, src32, dst32, counts,
        W_x, W_e, W_ff1, W_ff2, wxT, weT, wff1T, wff2T);
    scan_kernel<<<1, 256, 0, stream>>>(counts, row_start);
    fill_kernel<<<(N_EDGES + 255) / 256, 256, 0, stream>>>(src32, dst32, row_start,
                                                           fillc, perm, csr_src);

    // e-GEMM->fp8 (scatter to CSR slots) + h0 = x @ W_x in one dispatch
    egemm_h0<<<EGEMM_BLOCKS + 157, 256, 0, stream>>>(edge_attr, weT, e_fp8, perm,
                                                     x, wxT, h0b);

    hop_kernel<<<N_NODES / 4, 256, 0, stream>>>(h0b, nullptr, e_fp8, row_start, csr_src, h1b);
    hop_kernel<<<N_NODES / 4, 256, 0, stream>>>(h1b, h0b,     e_fp8, row_start, csr_src, h2b);
    hop_kernel<<<N_NODES / 4, 256, 0, stream>>>(h2b, h1b,     e_fp8, row_start, csr_src, h3b);

    attn_kernel<<<N_NODES, 256, 0, stream>>>(h0b, h1b, h2b, h3b, att_a, attnb);

    // hidden = relu(attn @ W_ff1) -> bf16
    wgemm<true, 1><<<dim3(157, 2), 256, 0, stream>>>(attnb, wff1T, hidb,
        N_NODES, DIM, FF_HIDDEN, nullptr, nullptr);
    // d_out = x + relu(attn + hidden @ W_ff2)
    wgemm<true, 2><<<dim3(157, 1), 256, 0, stream>>>(hidb, wff2T, d_out,
        N_NODES, FF_HIDDEN, DIM, attnb, x);
}

// Round 18
// 342.355 us; speedup vs baseline: 1.2837x; 1.0090x over previous
//
#include <hip/hip_runtime.h>
#include <hip/hip_bf16.h>

#define N_NODES   10000
#define N_EDGES   320000
#define DIM       256
#define EDGE_DIM  64
#define FF_HIDDEN 512
#define GAMMA     0.5f

typedef __attribute__((ext_vector_type(8))) short bf16x8;
typedef __attribute__((ext_vector_type(4))) float f32x4;

static __device__ __forceinline__ unsigned short f2b(float f)
{
    union { __hip_bfloat16 b; unsigned short u; } c;
    c.b = __float2bfloat16(f);
    return c.u;
}
static __device__ __forceinline__ float b2fs(unsigned short u)
{
    union { unsigned u32; float f; } c;
    c.u32 = ((unsigned)u) << 16;
    return c.f;
}

// f32 -> fp8 e4m3fn (round-half-up, denormals flushed, clamp to 448).
static __device__ __forceinline__ unsigned f2fp8(float f)
{
    union { float f; unsigned u; } c; c.f = f;
    const unsigned s = (c.u >> 24) & 0x80u;
    int v = (int)(((c.u & 0x7FFFFFFFu) + 0x00080000u) >> 20) - 960;
    v = (v < 8) ? 0 : ((v > 126) ? 126 : v);
    return s | (unsigned)v;
}
// fp8 e4m3fn -> f32 (denormals -> 0)
static __device__ __forceinline__ float fp8tof(unsigned u)
{
    unsigned v = ((u & 0x7Fu) << 4) + 0x3C00u;
    v = (u & 0x78u) ? v : 0u;
    v |= (u & 0x80u) << 8;
    union { unsigned u; float f; } c; c.u = v << 16;
    return c.f;
}

static __device__ __forceinline__ bf16x8 load_a_frag(const float* __restrict__ p)
{
    const float4 f0 = *(const float4*)p;
    const float4 f1 = *(const float4*)(p + 4);
    bf16x8 r;
    r[0] = (short)f2b(f0.x); r[1] = (short)f2b(f0.y);
    r[2] = (short)f2b(f0.z); r[3] = (short)f2b(f0.w);
    r[4] = (short)f2b(f1.x); r[5] = (short)f2b(f1.y);
    r[6] = (short)f2b(f1.z); r[7] = (short)f2b(f1.w);
    return r;
}

// ---------------------------------------------------------------------------
__global__ __launch_bounds__(256) void detect_kernel(const unsigned* __restrict__ ei,
                                                     int* __restrict__ flag)
{
    __shared__ int bad;
    if (threadIdx.x == 0) bad = 0;
    __syncthreads();
    int b = 0;
    for (int i = threadIdx.x; i < 1024; i += 256)
        if (ei[2 * i + 1] != 0u) b = 1;
    if (b) atomicAdd(&bad, 1);
    __syncthreads();
    if (threadIdx.x == 0) *flag = (bad == 0) ? 1 : 0;
}

__global__ __launch_bounds__(256) void convert_kernel(const unsigned* __restrict__ ei,
                                                      const int* __restrict__ flag,
                                                      int* __restrict__ src, int* __restrict__ dst,
                                                      int* __restrict__ counts)
{
    const int i = blockIdx.x * 256 + threadIdx.x;
    if (i >= N_EDGES) return;
    const int f = *flag;
    int s, d;
    if (f) { s = (int)ei[2 * i]; d = (int)ei[2 * (N_EDGES + i)]; }
    else   { s = (int)ei[i];     d = (int)ei[N_EDGES + i]; }
    src[i] = s;
    dst[i] = d;
    atomicAdd(&counts[d], 1);
}

__global__ __launch_bounds__(256) void scan_kernel(const int* __restrict__ counts,
                                                   int* __restrict__ row_start)
{
    __shared__ int lds[256];
    const int t = threadIdx.x;
    int vals[40];
    int tot = 0;
    const int base = t * 40;
#pragma unroll
    for (int j = 0; j < 40; ++j) {
        const int idx = base + j;
        const int c = (idx < N_NODES) ? counts[idx] : 0;
        vals[j] = tot;
        tot += c;
    }
    lds[t] = tot;
    __syncthreads();
    for (int off = 1; off < 256; off <<= 1) {
        const int tmp = (t >= off) ? lds[t - off] : 0;
        __syncthreads();
        lds[t] += tmp;
        __syncthreads();
    }
    const int ebase = lds[t] - tot;
#pragma unroll
    for (int j = 0; j < 40; ++j) {
        const int idx = base + j;
        if (idx < N_NODES) row_start[idx] = ebase + vals[j];
    }
    if (t == 0) row_start[N_NODES] = N_EDGES;
}

// perm[edge] = CSR slot (for egemm scatter stores); csr_src[slot] = src node.
__global__ __launch_bounds__(256) void fill_kernel(const int* __restrict__ src,
                                                   const int* __restrict__ dst,
                                                   const int* __restrict__ row_start,
                                                   int* __restrict__ fillc,
                                                   int* __restrict__ perm,
                                                   int* __restrict__ csr_src)
{
    const int i = blockIdx.x * 256 + threadIdx.x;
    if (i >= N_EDGES) return;
    const int d = dst[i];
    const int pos = atomicAdd(&fillc[d], 1);
    const int slot = row_start[d] + pos;
    perm[i] = slot;
    csr_src[slot] = src[i];
}

// ---------------------------------------------------------------------------
__global__ __launch_bounds__(256) void wconv_kernel(const float* __restrict__ W,
                                                    unsigned short* __restrict__ wT,
                                                    int K, int N)
{
    const int i = blockIdx.x * 256 + threadIdx.x;
    if (i >= K * N) return;
    const int k = i / N, n = i - k * N;
    wT[(size_t)n * K + k] = f2b(W[i]);
}

// ---------------------------------------------------------------------------
// Wave-level register GEMM (no LDS), 4 waves/block, wave = 64x64 tile.
template <bool ABF16, int MODE>
__global__ __launch_bounds__(256) void wgemm(const void* __restrict__ Av,
                                             const unsigned short* __restrict__ wT,
                                             void* __restrict__ outv,
                                             int M, int K, int N,
                                             const unsigned short* __restrict__ epi_a,
                                             const float* __restrict__ epi_x)
{
    const int tid  = threadIdx.x;
    const int wave = tid >> 6;
    const int lane = tid & 63;
    const int l15  = lane & 15;
    const int l4   = lane >> 4;
    const int m0   = blockIdx.x * 64;
    const int n0   = blockIdx.y * 256 + wave * 64;

    f32x4 acc[4][4];
#pragma unroll
    for (int i = 0; i < 4; ++i)
#pragma unroll
        for (int j = 0; j < 4; ++j) acc[i][j] = f32x4{0.f, 0.f, 0.f, 0.f};

    int rowm[4];
#pragma unroll
    for (int i = 0; i < 4; ++i) rowm[i] = min(m0 + i * 16 + l15, M - 1);

    const int nk = K >> 6;
    for (int kt = 0; kt < nk; ++kt) {
        const int kb = kt * 64 + l4 * 8;
        bf16x8 bfr[2][4], afr[2][4];
#pragma unroll
        for (int ks = 0; ks < 2; ++ks)
#pragma unroll
            for (int j = 0; j < 4; ++j)
                bfr[ks][j] = *(const bf16x8*)(wT + (size_t)(n0 + j * 16 + l15) * K + kb + ks * 32);
#pragma unroll
        for (int ks = 0; ks < 2; ++ks)
#pragma unroll
            for (int i = 0; i < 4; ++i) {
                if (ABF16)
                    afr[ks][i] = *(const bf16x8*)((const unsigned short*)Av + (size_t)rowm[i] * K + kb + ks * 32);
                else
                    afr[ks][i] = load_a_frag((const float*)Av + (size_t)rowm[i] * K + kb + ks * 32);
            }
#pragma unroll
        for (int ks = 0; ks < 2; ++ks)
#pragma unroll
            for (int i = 0; i < 4; ++i)
#pragma unroll
                for (int j = 0; j < 4; ++j)
                    acc[i][j] = __builtin_amdgcn_mfma_f32_16x16x32_bf16(bfr[ks][j], afr[ks][i], acc[i][j], 0, 0, 0);
    }

#pragma unroll
    for (int i = 0; i < 4; ++i) {
        const int m = m0 + i * 16 + l15;
        if (m < M) {
#pragma unroll
            for (int j = 0; j < 4; ++j) {
                const size_t oi = (size_t)m * N + n0 + j * 16 + l4 * 4;
                if (MODE == 2) {
                    const ushort4 ea = *(const ushort4*)(epi_a + oi);
                    const float4  ex = *(const float4*)(epi_x + oi);
                    float4 v;
                    v.x = fmaxf(acc[i][j][0] + b2fs(ea.x), 0.f) + ex.x;
                    v.y = fmaxf(acc[i][j][1] + b2fs(ea.y), 0.f) + ex.y;
                    v.z = fmaxf(acc[i][j][2] + b2fs(ea.z), 0.f) + ex.z;
                    v.w = fmaxf(acc[i][j][3] + b2fs(ea.w), 0.f) + ex.w;
                    *(float4*)((float*)outv + oi) = v;
                } else {
                    float a0 = acc[i][j][0], a1 = acc[i][j][1];
                    float a2 = acc[i][j][2], a3 = acc[i][j][3];
                    if (MODE == 1) {
                        a0 = fmaxf(a0, 0.f); a1 = fmaxf(a1, 0.f);
                        a2 = fmaxf(a2, 0.f); a3 = fmaxf(a3, 0.f);
                    }
                    ushort4 u;
                    u.x = f2b(a0); u.y = f2b(a1); u.z = f2b(a2); u.w = f2b(a3);
                    *(ushort4*)((unsigned short*)outv + oi) = u;
                }
            }
        }
    }
}

// ---------------------------------------------------------------------------
// e-GEMM -> fp8, scatter-store flavor (r13-best): block owns 64 consecutive
// edges (sequential reads); fp8-encode through 64x272B LDS; store scatters
// each 256B row (4 full 64B lines) to CSR slot perm[edge].
__global__ __launch_bounds__(256) void egemm_fp8(const float* __restrict__ A,
                                                 const unsigned short* __restrict__ wT,
                                                 unsigned char* __restrict__ e_out,
                                                 const int* __restrict__ perm)
{
    __shared__ unsigned char et[64 * 272];   // 17408 B
    const int tid  = threadIdx.x;
    const int wave = tid >> 6;
    const int lane = tid & 63;
    const int l15  = lane & 15;
    const int l4   = lane >> 4;
    const int wc0  = wave * 64;
    const int m0   = blockIdx.x * 64;   // edge base (sequential)

    bf16x8 bfr[2][4];
#pragma unroll
    for (int ks = 0; ks < 2; ++ks)
#pragma unroll
        for (int j = 0; j < 4; ++j)
            bfr[ks][j] = *(const bf16x8*)(wT + (size_t)(wc0 + j * 16 + l15) * 64 + ks * 32 + l4 * 8);

    bf16x8 afr[2][4];
#pragma unroll
    for (int ks = 0; ks < 2; ++ks)
#pragma unroll
        for (int i = 0; i < 4; ++i)
            afr[ks][i] = load_a_frag(A + (size_t)(m0 + i * 16 + l15) * 64 + ks * 32 + l4 * 8);

    f32x4 acc[4][4];
#pragma unroll
    for (int i = 0; i < 4; ++i)
#pragma unroll
        for (int j = 0; j < 4; ++j) acc[i][j] = f32x4{0.f, 0.f, 0.f, 0.f};
#pragma unroll
    for (int ks = 0; ks < 2; ++ks)
#pragma unroll
        for (int i = 0; i < 4; ++i)
#pragma unroll
            for (int j = 0; j < 4; ++j)
                acc[i][j] = __builtin_amdgcn_mfma_f32_16x16x32_bf16(bfr[ks][j], afr[ks][i], acc[i][j], 0, 0, 0);

#pragma unroll
    for (int i = 0; i < 4; ++i)
#pragma unroll
        for (int j = 0; j < 4; ++j) {
            const unsigned p = f2fp8(acc[i][j][0])
                             | (f2fp8(acc[i][j][1]) << 8)
                             | (f2fp8(acc[i][j][2]) << 16)
                             | (f2fp8(acc[i][j][3]) << 24);
            *(unsigned*)(&et[(i * 16 + l15) * 272 + wc0 + j * 16 + l4 * 4]) = p;
        }
    __syncthreads();

    const int row  = tid >> 2;
    const int orow = perm[m0 + row];
    const unsigned char* sp = et + row * 272 + (tid & 3) * 64;
    unsigned char* dp = e_out + (size_t)orow * 256 + (tid & 3) * 64;
#pragma unroll
    for (int v = 0; v < 4; ++v)
        *(uint4*)(dp + v * 16) = *(const uint4*)(sp + v * 16);
}

// ---------------------------------------------------------------------------
// Hop (r13-best): wave-per-node, 4 dims/lane, 8-edge MLP unroll.
// e fp8 in CSR order (sequential 256B rows); h bf16 full-row gathers.
__global__ __launch_bounds__(256) void hop_kernel(const unsigned short* __restrict__ h_prev1,
                                                  const unsigned short* __restrict__ h_prev2,
                                                  const unsigned char* __restrict__ e,
                                                  const int* __restrict__ row_start,
                                                  const int* __restrict__ csr_src,
                                                  unsigned short* __restrict__ h_out)
{
    const int wave = threadIdx.x >> 6;
    const int lane = threadIdx.x & 63;
    const int n = blockIdx.x * 4 + wave;
    const int d4 = lane * 4;
    const int rb = row_start[n];
    const int re = row_start[n + 1];

    float4 acc = {0.f, 0.f, 0.f, 0.f};
    int s = rb;
    for (; s + 8 <= re; s += 8) {
        int idx[8];
        unsigned ev[8];
        ushort4 hv[8];
#pragma unroll
        for (int u = 0; u < 8; ++u) idx[u] = csr_src[s + u];
#pragma unroll
        for (int u = 0; u < 8; ++u) ev[u] = *(const unsigned*)(e + (size_t)(s + u) * 256 + d4);
#pragma unroll
        for (int u = 0; u < 8; ++u) hv[u] = *(const ushort4*)(h_prev1 + (size_t)idx[u] * DIM + d4);
#pragma unroll
        for (int u = 0; u < 8; ++u) {
            acc.x += fmaxf(b2fs(hv[u].x) + fp8tof(ev[u] & 255u), 0.f);
            acc.y += fmaxf(b2fs(hv[u].y) + fp8tof((ev[u] >> 8) & 255u), 0.f);
            acc.z += fmaxf(b2fs(hv[u].z) + fp8tof((ev[u] >> 16) & 255u), 0.f);
            acc.w += fmaxf(b2fs(hv[u].w) + fp8tof(ev[u] >> 24), 0.f);
        }
    }
    for (; s < re; ++s) {
        const int sr = csr_src[s];
        const unsigned ev = *(const unsigned*)(e + (size_t)s * 256 + d4);
        const ushort4 hv = *(const ushort4*)(h_prev1 + (size_t)sr * DIM + d4);
        acc.x += fmaxf(b2fs(hv.x) + fp8tof(ev & 255u), 0.f);
        acc.y += fmaxf(b2fs(hv.y) + fp8tof((ev >> 8) & 255u), 0.f);
        acc.z += fmaxf(b2fs(hv.z) + fp8tof((ev >> 16) & 255u), 0.f);
        acc.w += fmaxf(b2fs(hv.w) + fp8tof(ev >> 24), 0.f);
    }
    if (h_prev2) {
        const float gd = GAMMA * (float)(re - rb);
        const ushort4 p2 = *(const ushort4*)(h_prev2 + (size_t)n * DIM + d4);
        acc.x -= gd * b2fs(p2.x); acc.y -= gd * b2fs(p2.y);
        acc.z -= gd * b2fs(p2.z); acc.w -= gd * b2fs(p2.w);
    }
    ushort4 o;
    o.x = f2b(acc.x); o.y = f2b(acc.y); o.z = f2b(acc.z); o.w = f2b(acc.w);
    *(ushort4*)(h_out + (size_t)n * DIM + d4) = o;
}

// ---------------------------------------------------------------------------
__global__ __launch_bounds__(256) void attn_kernel(const unsigned short* __restrict__ h0,
                                                   const unsigned short* __restrict__ h1,
                                                   const unsigned short* __restrict__ h2,
                                                   const unsigned short* __restrict__ h3,
                                                   const float* __restrict__ att_a,
                                                   unsigned short* __restrict__ out)
{
    const int n = blockIdx.x;
    const int t = threadIdx.x;
    const size_t i = (size_t)n * DIM + t;
    const float q = b2fs(h0[i]);
    float hk[4];
    hk[0] = q; hk[1] = b2fs(h1[i]); hk[2] = b2fs(h2[i]); hk[3] = b2fs(h3[i]);
    const float a = att_a[t];
    float sc[4];
#pragma unroll
    for (int k = 0; k < 4; ++k) {
        float v = tanhf(hk[k] + q) * a;
#pragma unroll
        for (int off = 32; off > 0; off >>= 1)
            v += __shfl_xor(v, off, 64);
        sc[k] = v;
    }
    const float mx = fmaxf(fmaxf(sc[0], sc[1]), fmaxf(sc[2], sc[3]));
    float ex[4], se = 0.f;
#pragma unroll
    for (int k = 0; k < 4; ++k) { ex[k] = __expf(sc[k] - mx); se += ex[k]; }
    const float inv = 1.f / se;
    float o = 0.f;
#pragma unroll
    for (int k = 0; k < 4; ++k) o += ex[k] * inv * hk[k];
    out[i] = f2b(o);
}

// ---------------------------------------------------------------------------
extern "C" void kernel_launch(void* const* d_in, const int* in_sizes, int n_in,
                              void* d_out, int out_size, void* d_ws, size_t ws_size,
                              hipStream_t stream)
{
    const float*    x         = (const float*)d_in[0];
    const unsigned* ei        = (const unsigned*)d_in[1];
    const float*    edge_attr = (const float*)d_in[2];
    const float*    W_x       = (const float*)d_in[3];
    const float*    W_e       = (const float*)d_in[4];
    const float*    att_a     = (const float*)d_in[5];
    const float*    W_ff1     = (const float*)d_in[6];
    const float*    W_ff2     = (const float*)d_in[7];

    char* ws = (char*)d_ws;
    size_t off = 0;
    auto alloc = [&](size_t bytes) -> void* {
        void* p = ws + off;
        off = (off + bytes + 255) & ~(size_t)255;
        return p;
    };
    int*   flag      = (int*)alloc(4);
    int*   src32     = (int*)alloc((size_t)N_EDGES * 4);
    int*   dst32     = (int*)alloc((size_t)N_EDGES * 4);
    int*   counts    = (int*)alloc((size_t)2 * N_NODES * 4);
    int*   fillc     = counts + N_NODES;
    int*   row_start = (int*)alloc((size_t)(N_NODES + 1) * 4);
    int*   perm      = (int*)alloc((size_t)N_EDGES * 4);
    int*   csr_src   = (int*)alloc((size_t)N_EDGES * 4);
    unsigned char*  e_fp8 = (unsigned char*)alloc((size_t)N_EDGES * DIM);
    unsigned short* h0b   = (unsigned short*)alloc((size_t)N_NODES * DIM * 2);
    unsigned short* h1b   = (unsigned short*)alloc((size_t)N_NODES * DIM * 2);
    unsigned short* h2b   = (unsigned short*)alloc((size_t)N_NODES * DIM * 2);
    unsigned short* h3b   = (unsigned short*)alloc((size_t)N_NODES * DIM * 2);
    unsigned short* attnb = (unsigned short*)alloc((size_t)N_NODES * DIM * 2);
    unsigned short* hidb  = (unsigned short*)alloc((size_t)N_NODES * FF_HIDDEN * 2);
    unsigned short* wxT   = (unsigned short*)alloc((size_t)DIM * DIM * 2);
    unsigned short* weT   = (unsigned short*)alloc((size_t)DIM * EDGE_DIM * 2);
    unsigned short* wff1T = (unsigned short*)alloc((size_t)FF_HIDDEN * DIM * 2);
    unsigned short* wff2T = (unsigned short*)alloc((size_t)DIM * FF_HIDDEN * 2);
    if (off > ws_size) return;

    const int egrid = (N_EDGES + 255) / 256;

    hipMemsetAsync(counts, 0, (size_t)2 * N_NODES * 4, stream);
    detect_kernel<<<1, 256, 0, stream>>>(ei, flag);
    convert_kernel<<<egrid, 256, 0, stream>>>(ei, flag, src32, dst32, counts);
    scan_kernel<<<1, 256, 0, stream>>>(counts, row_start);
    fill_kernel<<<egrid, 256, 0, stream>>>(src32, dst32, row_start, fillc, perm, csr_src);

    wconv_kernel<<<(DIM * DIM + 255) / 256, 256, 0, stream>>>(W_x, wxT, DIM, DIM);
    wconv_kernel<<<(EDGE_DIM * DIM + 255) / 256, 256, 0, stream>>>(W_e, weT, EDGE_DIM, DIM);
    wconv_kernel<<<(DIM * FF_HIDDEN + 255) / 256, 256, 0, stream>>>(W_ff1, wff1T, DIM, FF_HIDDEN);
    wconv_kernel<<<(FF_HIDDEN * DIM + 255) / 256, 256, 0, stream>>>(W_ff2, wff2T, FF_HIDDEN, DIM);

    // h0 = x @ W_x -> bf16
    wgemm<false, 0><<<dim3(157, 1), 256, 0, stream>>>(x, wxT, h0b,
        N_NODES, DIM, DIM, nullptr, nullptr);
    // e = edge_attr @ W_e -> fp8, sequential reads, CSR scatter stores
    egemm_fp8<<<N_EDGES / 64, 256, 0, stream>>>(edge_attr, weT, e_fp8, perm);

    hop_kernel<<<N_NODES / 4, 256, 0, stream>>>(h0b, nullptr, e_fp8, row_start, csr_src, h1b);
    hop_kernel<<<N_NODES / 4, 256, 0, stream>>>(h1b, h0b,     e_fp8, row_start, csr_src, h2b);
    hop_kernel<<<N_NODES / 4, 256, 0, stream>>>(h2b, h1b,     e_fp8, row_start, csr_src, h3b);

    attn_kernel<<<N_NODES, 256, 0, stream>>>(h0b, h1b, h2b, h3b, att_a, attnb);

    // hidden = relu(attn @ W_ff1) -> bf16
    wgemm<true, 1><<<dim3(157, 2), 256, 0, stream>>>(attnb, wff1T, hidb,
        N_NODES, DIM, FF_HIDDEN, nullptr, nullptr);
    // d_out = x + relu(attn + hidden @ W_ff2)
    wgemm<true, 2><<<dim3(157, 1), 256, 0, stream>>>(hidb, wff2T, d_out,
        N_NODES, FF_HIDDEN, DIM, attnb, x);
}